// Round 20
// baseline (27.870 us; speedup 1.0000x reference)
//
#include <hip/hip_runtime.h>
#include <math.h>

// RandISH v10: PRODUCER/CONSUMER WAVE SPECIALIZATION.
//   out[b, 2n+0] = Al(deg_n, r_b) * y0_norm[n] * P_l(ct)
//   out[b, 2n+1] = Al * cscale[n] * (-1)^deg * Re[(rx + i*ry)^deg]
// rv = vec[b] @ M[n]; rotation preserves |vec|=1 -> no normalization.
//
// Evidence: R17 doubled-stores = FREE; R18 VALU cut = FREE -> neither pipe
// binds. The binding path is each wave's serial chain: stores create vmcnt
// debt that WAR register reuse forces the compiler to drain before the
// wave's next compute (R14's lgkm-only barriers couldn't fix this).
// FIX: split roles. Producer waves (0-1) NEVER issue global stores ->
// their compute is never vmcnt-gated. Consumer waves (2-3) only
// ds_read + NT-store with ALTERNATING register sets -> a set's stores get
// a full ring phase to drain before WAR. Barriers are lgkm-only.
//
// Block 256 thr = 4 waves, 4 tiles/block, 2 LDS buffers [64][65] (33.3 KB)
// -> grid 1024 = 4 blocks/CU, all resident (16 waves/CU).
// Producer p handles bases 16p..16p+15 (wave-uniform SGPR constants,
// uniform branches, deg==1 fast path ~58% of bases, short recurrences).
// Consumer: 8 chunks/lane/tile; consecutive lanes -> consecutive 16B ->
// 1KB/wave full-line NT runs (best measured shape).
// Ring hazard check (lgkm-only barriers): phase it: consumers read
// buf[it&1], producers write buf[(it+1)&1] (disjoint); reads/writes are
// lgkm-complete at each barrier; buf[it&1] is overwritten in phase it+1
// only after the barrier that followed the consumer's completed reads.
//
// Re[z^d]: R_k = 2x R_{k-1} - (x^2+y^2) R_{k-2},  R_0=1, R_1=x.
// Al = exp2(-0.5*log2e*d(d+1)*(r+eps))  (0.5/(1/(r+e)+e) ~= 0.5(r+e), 1e-8).

#define NBASIS 32
#define PLEN 10
#define EPSV 1e-8f
#define LOG2E 1.44269504088896340736f
#define ROWD 65    // LDS row stride in dwords (odd -> conflict-free writes)
#define NTILE 4    // tiles per block

// LDS-only barrier: ds ops ordered; global stores free-run across it.
#define BAR_LDS()  do {                                           \
    asm volatile("s_waitcnt lgkmcnt(0)" ::: "memory");            \
    __builtin_amdgcn_s_barrier();                                 \
} while (0)

typedef float f32x4 __attribute__((ext_vector_type(4)));

__global__ __launch_bounds__(256) void randish_kernel(
    const float* __restrict__ vec,        // (B,3)
    const float* __restrict__ rough,      // (B,)
    const float* __restrict__ mats,       // (32,3,3)
    const float* __restrict__ coeffs,     // (32,10) increasing power
    const float* __restrict__ cscale,     // (32,)
    const float* __restrict__ y0n,        // (32,)
    const int*   __restrict__ degs,       // (32,)
    float* __restrict__ out,              // (B,64)
    int B)
{
    __shared__ float lds[2][64 * ROWD];   // 33.3 KB -> 4 blocks/CU

    const int t    = threadIdx.x;         // 0..255
    const int lane = t & 63;
    const int wid  = t >> 6;              // 0,1 = producers; 2,3 = consumers

    if (wid < 2) {
        // ================= PRODUCER (no global stores, ever) =============
        const int p = wid;                // bases 16p .. 16p+15

        // prefetch all tiles' inputs (independent loads, one window)
        float V0[NTILE], V1[NTILE], V2[NTILE], TC[NTILE];
#pragma unroll
        for (int it = 0; it < NTILE; ++it) {
            const int b = (blockIdx.x * NTILE + it) * 64 + lane;
            V0[it] = vec[b * 3 + 0];
            V1[it] = vec[b * 3 + 1];
            V2[it] = vec[b * 3 + 2];
            TC[it] = (rough[b] + EPSV) * (-0.5f * LOG2E);
        }

        auto compute_tile = [&](int it, int buf) {
            const float v0 = V0[it], v1 = V1[it], v2 = V2[it], tc = TC[it];
            float* row = &lds[buf][lane * ROWD];
#pragma unroll
            for (int j = 0; j < 16; ++j) {
                const int n = __builtin_amdgcn_readfirstlane(16 * p + j);
                const int d = __builtin_amdgcn_readfirstlane(degs[n]);

                const float xh = fmaf(v0, mats[n*9+0], fmaf(v1, mats[n*9+3], v2 * mats[n*9+6]));
                const float yh = fmaf(v0, mats[n*9+1], fmaf(v1, mats[n*9+4], v2 * mats[n*9+7]));
                const float ct = fmaf(v0, mats[n*9+2], fmaf(v1, mats[n*9+5], v2 * mats[n*9+8]));

                const float al = __builtin_amdgcn_exp2f((float)(d * (d + 1)) * tc);

                float y0v, yl1v;
                if (d == 1) {             // fast path (~58% of bases)
                    y0v  = y0n[n] * ct;
                    yl1v = -cscale[n] * xh;
                } else {
                    const int par  = d & 1;
                    const int base = n * PLEN + par;
                    const float ct2 = ct * ct;
                    const int K = d >> 1;          // 1..4
                    float v;
                    if (K == 1) {
                        v = fmaf(coeffs[base+2], ct2, coeffs[base]);
                    } else if (K == 2) {
                        v = fmaf(coeffs[base+4], ct2, coeffs[base+2]);
                        v = fmaf(v, ct2, coeffs[base]);
                    } else if (K == 3) {
                        v = fmaf(coeffs[base+6], ct2, coeffs[base+4]);
                        v = fmaf(v, ct2, coeffs[base+2]);
                        v = fmaf(v, ct2, coeffs[base]);
                    } else {
                        v = fmaf(coeffs[base+8], ct2, coeffs[base+6]);
                        v = fmaf(v, ct2, coeffs[base+4]);
                        v = fmaf(v, ct2, coeffs[base+2]);
                        v = fmaf(v, ct2, coeffs[base]);
                    }
                    if (par) v *= ct;

                    const float ss  = fmaf(yh, yh, xh * xh);
                    const float m2x = xh + xh;
                    float Rm2 = 1.0f, Rm1 = xh;
                    for (int k = 2; k <= d; ++k) {
                        const float Rk = fmaf(m2x, Rm1, -(ss * Rm2));
                        Rm2 = Rm1;
                        Rm1 = Rk;
                    }
                    float cs = cscale[n];
                    if (par) cs = -cs;
                    y0v  = y0n[n] * v;
                    yl1v = cs * Rm1;
                }
                row[2 * n + 0] = al * y0v;
                row[2 * n + 1] = al * yl1v;
            }
        };

        compute_tile(0, 0);
        BAR_LDS();                                    // buf0 ready
#pragma unroll
        for (int it = 0; it < NTILE - 1; ++it) {
            compute_tile(it + 1, (it + 1) & 1);       // disjoint from consumers
            BAR_LDS();
        }
        // producers exit; consumers' last reads need no further barrier
    } else {
        // ================= CONSUMER (only ds_read + NT store) ============
        const int cl = t - 128;                       // 0..127

        BAR_LDS();                                    // wait buf0
        f32x4 oA[8], oB[8];                           // alternating sets:
                                                      // one full phase of
                                                      // drain before WAR
#pragma unroll
        for (int it = 0; it < NTILE; ++it) {
            f32x4* o = (it & 1) ? oB : oA;
            const int buf = it & 1;
#pragma unroll
            for (int k = 0; k < 8; ++k) {             // 1024 chunks / 128 thr
                const int c  = k * 128 + cl;          // chunk index in tile
                const int r  = c >> 4;
                const int c4 = (c & 15) * 4;
                const float* src = &lds[buf][r * ROWD + c4];
                o[k] = f32x4{ src[0], src[1], src[2], src[3] };
            }
            f32x4* outp = reinterpret_cast<f32x4*>(
                out + (size_t)(blockIdx.x * NTILE + it) * 64 * 64);
#pragma unroll
            for (int k = 0; k < 8; ++k)               // 1KB/wave NT runs
                __builtin_nontemporal_store(o[k], outp + k * 128 + cl);

            if (it < NTILE - 1) BAR_LDS();            // lgkm-only: stores
                                                      // keep draining
        }
    }
}

extern "C" void kernel_launch(void* const* d_in, const int* in_sizes, int n_in,
                              void* d_out, int out_size, void* d_ws, size_t ws_size,
                              hipStream_t stream) {
    const float* vec    = (const float*)d_in[0];
    const float* rough  = (const float*)d_in[1];
    const float* mats   = (const float*)d_in[2];
    const float* coeffs = (const float*)d_in[3];
    const float* cscale = (const float*)d_in[4];
    const float* y0n    = (const float*)d_in[5];
    const int*   degs   = (const int*)d_in[6];
    float* out = (float*)d_out;

    const int B = in_sizes[1];            // roughness element count (262144)
    const int block = 256;                // 2 producer + 2 consumer waves
    const int grid = B / (64 * NTILE);    // 1024 blocks -> 4/CU, all resident

    randish_kernel<<<grid, block, 0, stream>>>(vec, rough, mats, coeffs, cscale,
                                               y0n, degs, out, B);
}

// Round 21
// 20.492 us; speedup vs baseline: 1.3600x; 1.3600x over previous
//
#include <hip/hip_runtime.h>
#include <math.h>

// RandISH v11: R18 (best, 20.37us) + PER-BLOCK PHASE SKEW.
//   out[b, 2n+0] = Al(deg_n, r_b) * y0_norm[n] * P_l(ct)
//   out[b, 2n+1] = Al * cscale[n] * (-1)^deg * Re[(rx + i*ry)^deg]
// rv = vec[b] @ M[n]; rotation preserves |vec|=1 -> no normalization.
//
// Plateau model: all blocks launch at t=0 with identical phase lengths ->
// the 8 co-resident blocks/CU run {compute}/{store} IN PHASE; the store
// pipe idles during collective compute and queues during collective store
// (fill kernel proves 6.5TB/s needs only continuous issue -- 8% occupancy).
// R15/R16 decorrelated by removing barriers but degraded store shape.
// Here: keep R18 EXACTLY (optimal 1KB/wave NT full-line runs), and skew
// each block's start by ((blockIdx>>8)&7) x ~512 cycles (blocks sharing a
// CU under round-robin dispatch differ by 256 in id -> distinct skews,
// max ~1.5us). Store phases interleave across co-resident blocks.
//
// Structure (R18): block 256 thr = 4 waves, 2 tiles/block, LDS [64][65]
// (odd stride, conflict-free), grid 2048 = 8 blocks/CU all resident;
// lane=b (coalesced loads), wave w -> bases 8w..8w+7 (wave-uniform SGPR
// constants, uniform branches, deg==1 fast path ~58%, short recurrences);
// NT stores: consecutive threads -> consecutive 16B -> 1KB/wave runs.
//
// Re[z^d]: R_k = 2x R_{k-1} - (x^2+y^2) R_{k-2},  R_0=1, R_1=x.
// Al = exp2(-0.5*log2e*d(d+1)*(r+eps))  (0.5/(1/(r+e)+e) ~= 0.5(r+e), 1e-8).

#define NBASIS 32
#define PLEN 10
#define EPSV 1e-8f
#define LOG2E 1.44269504088896340736f
#define ROWD 65    // LDS row stride in dwords (odd -> conflict-free)
#define NT 2       // tiles per block

typedef float f32x4 __attribute__((ext_vector_type(4)));

__global__ __launch_bounds__(256) void randish_kernel(
    const float* __restrict__ vec,        // (B,3)
    const float* __restrict__ rough,      // (B,)
    const float* __restrict__ mats,       // (32,3,3)
    const float* __restrict__ coeffs,     // (32,10) increasing power
    const float* __restrict__ cscale,     // (32,)
    const float* __restrict__ y0n,        // (32,)
    const int*   __restrict__ degs,       // (32,)
    float* __restrict__ out,              // (B,64)
    int B)
{
    __shared__ float lds[64 * ROWD];      // 16.6 KB -> 8 blocks/CU (grid-capped)

    // ---- phase skew: decorrelate co-resident blocks (wave-uniform) ----
    {
        const int skew = (blockIdx.x >> 8) & 7;   // CU-mates differ by 256
        for (int i = 0; i < skew; ++i)
            __builtin_amdgcn_s_sleep(8);          // ~512 cycles each
    }

    const int t    = threadIdx.x;         // 0..255
    const int lane = t & 63;              // direction within tile
    const int w    = t >> 6;              // wave id 0..3

    // ---- prefetch BOTH tiles' inputs (independent loads, one window) ----
    float V0[NT], V1[NT], V2[NT], TC[NT];
    int   BB[NT];
#pragma unroll
    for (int it = 0; it < NT; ++it) {
        const int b0 = (blockIdx.x * NT + it) * 64;
        const int b  = b0 + lane;         // B % (64*NT) == 0 -> in range
        BB[it] = b0;
        V0[it] = vec[b * 3 + 0];
        V1[it] = vec[b * 3 + 1];
        V2[it] = vec[b * 3 + 2];
        // Al = exp2( d*(d+1) * tc ),  tc = -0.5*log2e*(r+eps)
        TC[it] = (rough[b] + EPSV) * (-0.5f * LOG2E);
    }

    float* row = &lds[lane * ROWD];

#pragma unroll
    for (int it = 0; it < NT; ++it) {
        const float v0 = V0[it], v1 = V1[it], v2 = V2[it], tc = TC[it];

        // ---- compute tile into LDS ----
#pragma unroll
        for (int j = 0; j < 8; ++j) {
            // n and all derived per-n data are wave-uniform -> SGPRs
            const int n = __builtin_amdgcn_readfirstlane(8 * w + j);
            const int d = __builtin_amdgcn_readfirstlane(degs[n]);

            // rotate (|rv| == 1); mats entries are uniform scalar operands
            const float xh = fmaf(v0, mats[n*9+0], fmaf(v1, mats[n*9+3], v2 * mats[n*9+6]));
            const float yh = fmaf(v0, mats[n*9+1], fmaf(v1, mats[n*9+4], v2 * mats[n*9+7]));
            const float ct = fmaf(v0, mats[n*9+2], fmaf(v1, mats[n*9+5], v2 * mats[n*9+8]));

            const float al = __builtin_amdgcn_exp2f((float)(d * (d + 1)) * tc);

            float y0v, yl1v;
            if (d == 1) {
                // P1(ct) = ct exactly; Re[z^1] = xh; (-1)^1 fold
                y0v  = y0n[n] * ct;
                yl1v = -cscale[n] * xh;
            } else {
                const int par  = d & 1;
                const int base = n * PLEN + par;   // uniform runtime offset
                const float ct2 = ct * ct;

                // Horner with exactly (d>>1)+1 terms (uniform branch tree)
                const int K = d >> 1;              // 1..4 for d in [2,9]
                float v;
                if (K == 1) {
                    v = fmaf(coeffs[base+2], ct2, coeffs[base]);
                } else if (K == 2) {
                    v = fmaf(coeffs[base+4], ct2, coeffs[base+2]);
                    v = fmaf(v, ct2, coeffs[base]);
                } else if (K == 3) {
                    v = fmaf(coeffs[base+6], ct2, coeffs[base+4]);
                    v = fmaf(v, ct2, coeffs[base+2]);
                    v = fmaf(v, ct2, coeffs[base]);
                } else {
                    v = fmaf(coeffs[base+8], ct2, coeffs[base+6]);
                    v = fmaf(v, ct2, coeffs[base+4]);
                    v = fmaf(v, ct2, coeffs[base+2]);
                    v = fmaf(v, ct2, coeffs[base]);
                }
                if (par) v *= ct;                  // uniform branch

                // Re[(xh+i*yh)^d]: d-1 iterations (uniform trip count)
                const float ss  = fmaf(yh, yh, xh * xh);
                const float m2x = xh + xh;
                float Rm2 = 1.0f, Rm1 = xh;
                for (int k = 2; k <= d; ++k) {
                    const float Rk = fmaf(m2x, Rm1, -(ss * Rm2));
                    Rm2 = Rm1;
                    Rm1 = Rk;
                }
                float cs = cscale[n];
                if (par) cs = -cs;                 // fold (-1)^deg, uniform

                y0v  = y0n[n] * v;
                yl1v = cs * Rm1;
            }

            // bank = (lane + 2n) % 32 -> <=2-way across 64 lanes (free)
            row[2 * n + 0] = al * y0v;
            row[2 * n + 1] = al * yl1v;
        }

        __syncthreads();

        // ---- store tile: 1024 dwordx4 chunks, 4/thread; consecutive
        //      threads -> consecutive 16B -> 1KB/wave full-line NT runs ----
        f32x4 o[4];
#pragma unroll
        for (int p = 0; p < 4; ++p) {
            const int c  = p * 256 + t;   // chunk index in tile
            const int r  = c >> 4;        // source LDS row
            const int c4 = (c & 15) * 4;  // dword column
            const float* src = &lds[r * ROWD + c4];
            o[p] = f32x4{ src[0], src[1], src[2], src[3] };
        }
        f32x4* outp = reinterpret_cast<f32x4*>(out + (size_t)BB[it] * 64);
#pragma unroll
        for (int p = 0; p < 4; ++p)
            __builtin_nontemporal_store(o[p], outp + p * 256 + t);

        if (it + 1 < NT) __syncthreads(); // LDS reuse guard
    }
}

extern "C" void kernel_launch(void* const* d_in, const int* in_sizes, int n_in,
                              void* d_out, int out_size, void* d_ws, size_t ws_size,
                              hipStream_t stream) {
    const float* vec    = (const float*)d_in[0];
    const float* rough  = (const float*)d_in[1];
    const float* mats   = (const float*)d_in[2];
    const float* coeffs = (const float*)d_in[3];
    const float* cscale = (const float*)d_in[4];
    const float* y0n    = (const float*)d_in[5];
    const int*   degs   = (const int*)d_in[6];
    float* out = (float*)d_out;

    const int B = in_sizes[1];            // roughness element count (262144)
    const int block = 256;                // 4 waves; 2 tiles of 64 directions
    const int grid = B / (64 * NT);       // 2048 blocks -> 8/CU, all resident

    randish_kernel<<<grid, block, 0, stream>>>(vec, rough, mats, coeffs, cscale,
                                               y0n, degs, out, B);
}

// Round 22
// 20.354 us; speedup vs baseline: 1.3693x; 1.0068x over previous
//
#include <hip/hip_runtime.h>
#include <math.h>

// RandISH v12: R18 + per-wave ASCENDING CONTIGUOUS 4KB store runs.
//   out[b, 2n+0] = Al(deg_n, r_b) * y0_norm[n] * P_l(ct)
//   out[b, 2n+1] = Al * cscale[n] * (-1)^deg * Re[(rx + i*ry)^deg]
// rv = vec[b] @ M[n]; rotation preserves |vec|=1 -> no normalization.
//
// Plateau forensics (R11..R20): insensitive to store volume (R17 2x free),
// VALU (R18 cut free), barrier semantics, specialization, phase skew. The
// only axis that ever moved perf is store-run SHAPE. Last untried lever:
// address-sequence locality. R18's wave w stores chunks {p*4KB + w*1KB} --
// 4 scattered 1KB runs per wave; the CU stream interleaves 16 waves'
// scattered runs (bad HBM page sequencing). Reindex c = w*256 + p*64 +
// lane: each wave emits one ascending CONTIGUOUS 4KB run (fill-kernel
// shape, the only measured-6.5TB/s stream on this chip).
//
// Structure (R18): block 256 thr = 4 waves, 2 tiles/block, LDS [64][65]
// (odd stride), grid 2048 = 8 blocks/CU all resident; lane=b, wave w ->
// bases 8w..8w+7 (wave-uniform SGPR constants, uniform branches, deg==1
// fast path ~58%, short recurrences); NT full-line stores.
//
// Re[z^d]: R_k = 2x R_{k-1} - (x^2+y^2) R_{k-2},  R_0=1, R_1=x.
// Al = exp2(-0.5*log2e*d(d+1)*(r+eps))  (0.5/(1/(r+e)+e) ~= 0.5(r+e), 1e-8).

#define NBASIS 32
#define PLEN 10
#define EPSV 1e-8f
#define LOG2E 1.44269504088896340736f
#define ROWD 65    // LDS row stride in dwords (odd -> conflict-free)
#define NT 2       // tiles per block

typedef float f32x4 __attribute__((ext_vector_type(4)));

__global__ __launch_bounds__(256) void randish_kernel(
    const float* __restrict__ vec,        // (B,3)
    const float* __restrict__ rough,      // (B,)
    const float* __restrict__ mats,       // (32,3,3)
    const float* __restrict__ coeffs,     // (32,10) increasing power
    const float* __restrict__ cscale,     // (32,)
    const float* __restrict__ y0n,        // (32,)
    const int*   __restrict__ degs,       // (32,)
    float* __restrict__ out,              // (B,64)
    int B)
{
    __shared__ float lds[64 * ROWD];      // 16.6 KB -> 8 blocks/CU (grid-capped)

    const int t    = threadIdx.x;         // 0..255
    const int lane = t & 63;              // direction within tile
    const int w    = t >> 6;              // wave id 0..3

    // ---- prefetch BOTH tiles' inputs (independent loads, one window) ----
    float V0[NT], V1[NT], V2[NT], TC[NT];
    int   BB[NT];
#pragma unroll
    for (int it = 0; it < NT; ++it) {
        const int b0 = (blockIdx.x * NT + it) * 64;
        const int b  = b0 + lane;         // B % (64*NT) == 0 -> in range
        BB[it] = b0;
        V0[it] = vec[b * 3 + 0];
        V1[it] = vec[b * 3 + 1];
        V2[it] = vec[b * 3 + 2];
        // Al = exp2( d*(d+1) * tc ),  tc = -0.5*log2e*(r+eps)
        TC[it] = (rough[b] + EPSV) * (-0.5f * LOG2E);
    }

    float* row = &lds[lane * ROWD];

#pragma unroll
    for (int it = 0; it < NT; ++it) {
        const float v0 = V0[it], v1 = V1[it], v2 = V2[it], tc = TC[it];

        // ---- compute tile into LDS ----
#pragma unroll
        for (int j = 0; j < 8; ++j) {
            // n and all derived per-n data are wave-uniform -> SGPRs
            const int n = __builtin_amdgcn_readfirstlane(8 * w + j);
            const int d = __builtin_amdgcn_readfirstlane(degs[n]);

            // rotate (|rv| == 1); mats entries are uniform scalar operands
            const float xh = fmaf(v0, mats[n*9+0], fmaf(v1, mats[n*9+3], v2 * mats[n*9+6]));
            const float yh = fmaf(v0, mats[n*9+1], fmaf(v1, mats[n*9+4], v2 * mats[n*9+7]));
            const float ct = fmaf(v0, mats[n*9+2], fmaf(v1, mats[n*9+5], v2 * mats[n*9+8]));

            const float al = __builtin_amdgcn_exp2f((float)(d * (d + 1)) * tc);

            float y0v, yl1v;
            if (d == 1) {
                // P1(ct) = ct exactly; Re[z^1] = xh; (-1)^1 fold
                y0v  = y0n[n] * ct;
                yl1v = -cscale[n] * xh;
            } else {
                const int par  = d & 1;
                const int base = n * PLEN + par;   // uniform runtime offset
                const float ct2 = ct * ct;

                // Horner with exactly (d>>1)+1 terms (uniform branch tree)
                const int K = d >> 1;              // 1..4 for d in [2,9]
                float v;
                if (K == 1) {
                    v = fmaf(coeffs[base+2], ct2, coeffs[base]);
                } else if (K == 2) {
                    v = fmaf(coeffs[base+4], ct2, coeffs[base+2]);
                    v = fmaf(v, ct2, coeffs[base]);
                } else if (K == 3) {
                    v = fmaf(coeffs[base+6], ct2, coeffs[base+4]);
                    v = fmaf(v, ct2, coeffs[base+2]);
                    v = fmaf(v, ct2, coeffs[base]);
                } else {
                    v = fmaf(coeffs[base+8], ct2, coeffs[base+6]);
                    v = fmaf(v, ct2, coeffs[base+4]);
                    v = fmaf(v, ct2, coeffs[base+2]);
                    v = fmaf(v, ct2, coeffs[base]);
                }
                if (par) v *= ct;                  // uniform branch

                // Re[(xh+i*yh)^d]: d-1 iterations (uniform trip count)
                const float ss  = fmaf(yh, yh, xh * xh);
                const float m2x = xh + xh;
                float Rm2 = 1.0f, Rm1 = xh;
                for (int k = 2; k <= d; ++k) {
                    const float Rk = fmaf(m2x, Rm1, -(ss * Rm2));
                    Rm2 = Rm1;
                    Rm1 = Rk;
                }
                float cs = cscale[n];
                if (par) cs = -cs;                 // fold (-1)^deg, uniform

                y0v  = y0n[n] * v;
                yl1v = cs * Rm1;
            }

            // bank = (lane + 2n) % 32 -> <=2-way across 64 lanes (free)
            row[2 * n + 0] = al * y0v;
            row[2 * n + 1] = al * yl1v;
        }

        __syncthreads();

        // ---- store tile: wave w owns the contiguous 4KB quarter
        //      [w*4KB, (w+1)*4KB); 4 ascending 1KB full-line NT runs ----
        f32x4 o[4];
#pragma unroll
        for (int p = 0; p < 4; ++p) {
            const int c  = w * 256 + p * 64 + lane;  // ascending per wave
            const int r  = c >> 4;        // source LDS row
            const int c4 = (c & 15) * 4;  // dword column
            const float* src = &lds[r * ROWD + c4];
            o[p] = f32x4{ src[0], src[1], src[2], src[3] };
        }
        f32x4* outp = reinterpret_cast<f32x4*>(out + (size_t)BB[it] * 64);
#pragma unroll
        for (int p = 0; p < 4; ++p)
            __builtin_nontemporal_store(o[p], outp + w * 256 + p * 64 + lane);

        if (it + 1 < NT) __syncthreads(); // LDS reuse guard
    }
}

extern "C" void kernel_launch(void* const* d_in, const int* in_sizes, int n_in,
                              void* d_out, int out_size, void* d_ws, size_t ws_size,
                              hipStream_t stream) {
    const float* vec    = (const float*)d_in[0];
    const float* rough  = (const float*)d_in[1];
    const float* mats   = (const float*)d_in[2];
    const float* coeffs = (const float*)d_in[3];
    const float* cscale = (const float*)d_in[4];
    const float* y0n    = (const float*)d_in[5];
    const int*   degs   = (const int*)d_in[6];
    float* out = (float*)d_out;

    const int B = in_sizes[1];            // roughness element count (262144)
    const int block = 256;                // 4 waves; 2 tiles of 64 directions
    const int grid = B / (64 * NT);       // 2048 blocks -> 8/CU, all resident

    randish_kernel<<<grid, block, 0, stream>>>(vec, rough, mats, coeffs, cscale,
                                               y0n, degs, out, B);
}